// Round 1
// baseline (1470.586 us; speedup 1.0000x reference)
//
#include <hip/hip_runtime.h>

#define Bv 64
#define Gv 4096
#define Cv 32
#define Sv 16
#define Lv 4
#define NSTEP 4
#define LOG2E 1.4426950408889634f
#define LN2   0.6931471805599453f
#define GAMMA 0.01f
#define RLOG2E_G 144.26950408889634f   // LOG2E / GAMMA

__device__ __forceinline__ float wave_max(float v) {
#pragma unroll
    for (int off = 32; off > 0; off >>= 1)
        v = fmaxf(v, __shfl_xor(v, off, 64));
    return v;
}

// 256-thread block -> one atomicMax (values are all >= 0, so int-bit compare == float compare)
__device__ __forceinline__ void block_atomic_max(float v, float* dst, float* smax) {
    v = wave_max(v);
    int lane = threadIdx.x & 63;
    int wid  = threadIdx.x >> 6;
    if (lane == 0) smax[wid] = v;
    __syncthreads();
    if (threadIdx.x == 0) {
        float m = fmaxf(fmaxf(smax[0], smax[1]), fmaxf(smax[2], smax[3]));
        atomicMax((int*)dst, __float_as_int(m));
    }
}

// x [B,G] -> Rt [G,B]   (LDS-tiled transpose, 64 g per block)
__global__ __launch_bounds__(256) void k_transpose(const float* __restrict__ x,
                                                   float* __restrict__ Rt) {
    __shared__ float tile[64][65];
    int g0 = blockIdx.x * 64;
#pragma unroll
    for (int i = 0; i < 16; ++i) {
        int t = threadIdx.x + i * 256;
        int b = t >> 6, gi = t & 63;
        tile[gi][b] = x[b * Gv + g0 + gi];
    }
    __syncthreads();
#pragma unroll
    for (int i = 0; i < 16; ++i) {
        int t = threadIdx.x + i * 256;
        int gi = t >> 6, b = t & 63;
        Rt[(g0 + gi) * 64 + b] = tile[gi][b];
    }
}

// One wave per (c,g): lane = batch b. ls[c,b,g] = gamma*LSE_s( prod_l Rt[I[c,g,s,l]*64+b] / gamma )
__global__ __launch_bounds__(256) void k_clauses(const float* __restrict__ Rt,
                                                 const int* __restrict__ I,
                                                 float* __restrict__ Cs,
                                                 float* __restrict__ Mc) {
    __shared__ float smax[4];
    int wid  = __builtin_amdgcn_readfirstlane((int)(threadIdx.x >> 6));
    int lane = threadIdx.x & 63;
    int wave = blockIdx.x * 4 + wid;          // 0 .. 131071
    int c = wave >> 12;                        // / 4096  (block never straddles c)
    int g = wave & 4095;
    const int* __restrict__ Ic = I + (size_t)(c * Gv + g) * (Sv * Lv);

    float raw[Sv];
#pragma unroll
    for (int s = 0; s < Sv; ++s) {
        float p = 1.0f;
#pragma unroll
        for (int l = 0; l < Lv; ++l) {
            int idx = Ic[s * Lv + l];          // wave-uniform -> scalar load
            p *= Rt[(idx << 6) + lane];        // coalesced 256B wave gather, L2-resident
        }
        raw[s] = p;
    }
    float m = raw[0];
#pragma unroll
    for (int s = 1; s < Sv; ++s) m = fmaxf(m, raw[s]);
    float sum = 0.0f;
#pragma unroll
    for (int s = 0; s < Sv; ++s)
        sum += exp2f((raw[s] - m) * RLOG2E_G);
    float ls = m + GAMMA * (LN2 * log2f(sum));

    Cs[(size_t)c * (Gv * 64) + (g << 6) + lane] = ls;
    block_atomic_max(ls, Mc + c, smax);        // c uniform across the block
}

// H[b,g] = sum_c softmax(W)[c] * Cs[c,b,g] / max(Mc[c],1) ; track global max
__global__ __launch_bounds__(256) void k_combine(const float* __restrict__ Cs,
                                                 const float* __restrict__ W,
                                                 const float* __restrict__ Mc,
                                                 float* __restrict__ H,
                                                 float* __restrict__ Hmax) {
    __shared__ float smax[4];
    int tid = blockIdx.x * 256 + threadIdx.x;
    float e[Cv];
    float wsum = 0.0f;
#pragma unroll
    for (int c = 0; c < Cv; ++c) { e[c] = exp2f(W[c] * LOG2E); wsum += e[c]; }
    float rw = 1.0f / wsum;
    float h = 0.0f;
#pragma unroll
    for (int c = 0; c < Cv; ++c) {
        float coef = e[c] * rw / fmaxf(Mc[c], 1.0f);
        h += coef * Cs[(size_t)c * (Gv * 64) + tid];
    }
    H[tid] = h;
    block_atomic_max(h, Hmax, smax);
}

// ls = softor2(R, H/max(Hmax,1)) un-normalized ; track global max
__global__ __launch_bounds__(256) void k_update(const float* __restrict__ Rt,
                                                const float* __restrict__ H,
                                                const float* __restrict__ Hmax,
                                                float* __restrict__ Lraw,
                                                float* __restrict__ Lmax) {
    __shared__ float smax[4];
    int tid = blockIdx.x * 256 + threadIdx.x;
    float hden = fmaxf(Hmax[0], 1.0f);
    float hn = H[tid] / hden;
    float r  = Rt[tid];
    float mx = fmaxf(r, hn), mn = fminf(r, hn);
    float t  = exp2f((mn - mx) * RLOG2E_G);
    float ls = mx + GAMMA * (LN2 * log2f(1.0f + t));
    Lraw[tid] = ls;
    block_atomic_max(ls, Lmax, smax);
}

// R = Lraw / max(Lmax,1); last step writes output in [B,G] layout
__global__ __launch_bounds__(256) void k_norm(const float* __restrict__ Lraw,
                                              const float* __restrict__ Lmax,
                                              float* __restrict__ Rt,
                                              float* __restrict__ out,
                                              int last) {
    int tid = blockIdx.x * 256 + threadIdx.x;
    float d = fmaxf(Lmax[0], 1.0f);
    float v = Lraw[tid] / d;
    if (last) {
        int g = tid >> 6, b = tid & 63;
        out[b * Gv + g] = v;
    } else {
        Rt[tid] = v;
    }
}

extern "C" void kernel_launch(void* const* d_in, const int* in_sizes, int n_in,
                              void* d_out, int out_size, void* d_ws, size_t ws_size,
                              hipStream_t stream) {
    const float* x = (const float*)d_in[0];   // [64, 4096]
    const float* W = (const float*)d_in[1];   // [1, 32]
    const int*   I = (const int*)d_in[2];     // [32, 4096, 16, 4]
    float* out = (float*)d_out;               // [64, 4096]

    float* ws   = (float*)d_ws;
    float* Rt   = ws;                  // 262144 floats  [G,B]
    float* H    = ws + 262144;         // 262144
    float* Lraw = ws + 524288;         // 262144
    float* maxb = ws + 786432;         // 4 steps * 64 floats of atomic buffers
    float* Cs   = ws + 1048576;        // 32 * 262144 = 8388608 floats (32 MB)

    hipMemsetAsync(maxb, 0, NSTEP * 64 * sizeof(float), stream);
    k_transpose<<<Gv / 64, 256, 0, stream>>>(x, Rt);

    for (int step = 0; step < NSTEP; ++step) {
        float* Mc = maxb + step * 64;  // [32] per-clause maxima
        float* Hm = Mc + 32;
        float* Lm = Mc + 33;
        k_clauses<<<(Cv * Gv) / 4, 256, 0, stream>>>(Rt, I, Cs, Mc);
        k_combine<<<(Bv * Gv) / 256, 256, 0, stream>>>(Cs, W, Mc, H, Hm);
        k_update <<<(Bv * Gv) / 256, 256, 0, stream>>>(Rt, H, Hm, Lraw, Lm);
        k_norm   <<<(Bv * Gv) / 256, 256, 0, stream>>>(Lraw, Lm, Rt, out, step == NSTEP - 1);
    }
}

// Round 2
// 887.957 us; speedup vs baseline: 1.6561x; 1.6561x over previous
//
#include <hip/hip_runtime.h>

#define Bv 64
#define Gv 4096
#define Cv 32
#define Sv 16
#define Lv 4
#define NSTEP 4
#define LOG2E 1.4426950408889634f
#define LN2   0.6931471805599453f
#define GAMMA 0.01f
#define RLOG2E_G 144.26950408889634f   // LOG2E / GAMMA

__device__ __forceinline__ float wave_max(float v) {
#pragma unroll
    for (int off = 32; off > 0; off >>= 1)
        v = fmaxf(v, __shfl_xor(v, off, 64));
    return v;
}

// 256-thread block -> one atomicMax (values all >= 0, so int-bit compare == float compare)
__device__ __forceinline__ void block_atomic_max(float v, float* dst, float* smax) {
    v = wave_max(v);
    int lane = threadIdx.x & 63;
    int wid  = threadIdx.x >> 6;
    if (lane == 0) smax[wid] = v;
    __syncthreads();
    if (threadIdx.x == 0) {
        float m = fmaxf(fmaxf(smax[0], smax[1]), fmaxf(smax[2], smax[3]));
        atomicMax((int*)dst, __float_as_int(m));
    }
}

// x [B,G] -> Rt [G,B]   (LDS-tiled transpose, 64 g per block)
__global__ __launch_bounds__(256) void k_transpose(const float* __restrict__ x,
                                                   float* __restrict__ Rt) {
    __shared__ float tile[64][65];
    int g0 = blockIdx.x * 64;
#pragma unroll
    for (int i = 0; i < 16; ++i) {
        int t = threadIdx.x + i * 256;
        int b = t >> 6, gi = t & 63;
        tile[gi][b] = x[b * Gv + g0 + gi];
    }
    __syncthreads();
#pragma unroll
    for (int i = 0; i < 16; ++i) {
        int t = threadIdx.x + i * 256;
        int gi = t >> 6, b = t & 63;
        Rt[(g0 + gi) * 64 + b] = tile[gi][b];
    }
}

// Lane = (g_sub 0..3, bg 0..15). Each lane owns batches 4bg..4bg+3 (float4) of
// grounding g = g0 + g_sub. One wave covers 4 g; block (4 waves) covers 16 g of one c.
// Per s: one int4 index load + 4 float4 gathers, product in-lane, p[16] staged in regs.
__global__ __launch_bounds__(256, 4) void k_clauses(const float4* __restrict__ Rt4,
                                                    const int4* __restrict__ I4,
                                                    float4* __restrict__ Cs4,
                                                    float* __restrict__ Mc) {
    __shared__ float smax[4];
    int lane = threadIdx.x & 63;
    int wid  = threadIdx.x >> 6;
    int bg   = lane & 15;
    int gsub = lane >> 4;
    int blk  = blockIdx.x;              // 8192 blocks
    int c    = blk >> 8;                // 256 blocks per clause
    int g    = ((blk & 255) << 4) + (wid << 2) + gsub;
    const int4* __restrict__ Ig = I4 + (size_t)(c * Gv + g) * Sv;

    float4 p[Sv];
#pragma unroll
    for (int s = 0; s < Sv; ++s) {
        int4 ii = Ig[s];
        float4 a = Rt4[((size_t)(unsigned)ii.x << 4) + bg];
        float4 b = Rt4[((size_t)(unsigned)ii.y << 4) + bg];
        float4 e = Rt4[((size_t)(unsigned)ii.z << 4) + bg];
        float4 d = Rt4[((size_t)(unsigned)ii.w << 4) + bg];
        p[s] = make_float4(a.x * b.x * e.x * d.x,
                           a.y * b.y * e.y * d.y,
                           a.z * b.z * e.z * d.z,
                           a.w * b.w * e.w * d.w);
    }

    float4 m = p[0];
#pragma unroll
    for (int s = 1; s < Sv; ++s) {
        m.x = fmaxf(m.x, p[s].x); m.y = fmaxf(m.y, p[s].y);
        m.z = fmaxf(m.z, p[s].z); m.w = fmaxf(m.w, p[s].w);
    }
    float4 sum = make_float4(0.f, 0.f, 0.f, 0.f);
#pragma unroll
    for (int s = 0; s < Sv; ++s) {
        sum.x += exp2f((p[s].x - m.x) * RLOG2E_G);
        sum.y += exp2f((p[s].y - m.y) * RLOG2E_G);
        sum.z += exp2f((p[s].z - m.z) * RLOG2E_G);
        sum.w += exp2f((p[s].w - m.w) * RLOG2E_G);
    }
    float4 ls;
    ls.x = m.x + GAMMA * (LN2 * log2f(sum.x));
    ls.y = m.y + GAMMA * (LN2 * log2f(sum.y));
    ls.z = m.z + GAMMA * (LN2 * log2f(sum.z));
    ls.w = m.w + GAMMA * (LN2 * log2f(sum.w));

    Cs4[((size_t)(c * Gv + g) << 4) + bg] = ls;

    float v = fmaxf(fmaxf(ls.x, ls.y), fmaxf(ls.z, ls.w));
    block_atomic_max(v, Mc + c, smax);      // c uniform across block
}

// H[b,g] = sum_c softmax(W)[c] * Cs[c,b,g] / max(Mc[c],1) ; track global max
__global__ __launch_bounds__(256) void k_combine(const float* __restrict__ Cs,
                                                 const float* __restrict__ W,
                                                 const float* __restrict__ Mc,
                                                 float* __restrict__ H,
                                                 float* __restrict__ Hmax) {
    __shared__ float smax[4];
    int tid = blockIdx.x * 256 + threadIdx.x;
    float e[Cv];
    float wsum = 0.0f;
#pragma unroll
    for (int c = 0; c < Cv; ++c) { e[c] = exp2f(W[c] * LOG2E); wsum += e[c]; }
    float rw = 1.0f / wsum;
    float h = 0.0f;
#pragma unroll
    for (int c = 0; c < Cv; ++c) {
        float coef = e[c] * rw / fmaxf(Mc[c], 1.0f);
        h += coef * Cs[(size_t)c * (Gv * 64) + tid];
    }
    H[tid] = h;
    block_atomic_max(h, Hmax, smax);
}

// ls = softor2(R, H/max(Hmax,1)) un-normalized ; track global max
__global__ __launch_bounds__(256) void k_update(const float* __restrict__ Rt,
                                                const float* __restrict__ H,
                                                const float* __restrict__ Hmax,
                                                float* __restrict__ Lraw,
                                                float* __restrict__ Lmax) {
    __shared__ float smax[4];
    int tid = blockIdx.x * 256 + threadIdx.x;
    float hden = fmaxf(Hmax[0], 1.0f);
    float hn = H[tid] / hden;
    float r  = Rt[tid];
    float mx = fmaxf(r, hn), mn = fminf(r, hn);
    float t  = exp2f((mn - mx) * RLOG2E_G);
    float ls = mx + GAMMA * (LN2 * log2f(1.0f + t));
    Lraw[tid] = ls;
    block_atomic_max(ls, Lmax, smax);
}

// R = Lraw / max(Lmax,1); last step writes output in [B,G] layout
__global__ __launch_bounds__(256) void k_norm(const float* __restrict__ Lraw,
                                              const float* __restrict__ Lmax,
                                              float* __restrict__ Rt,
                                              float* __restrict__ out,
                                              int last) {
    int tid = blockIdx.x * 256 + threadIdx.x;
    float d = fmaxf(Lmax[0], 1.0f);
    float v = Lraw[tid] / d;
    if (last) {
        int g = tid >> 6, b = tid & 63;
        out[b * Gv + g] = v;
    } else {
        Rt[tid] = v;
    }
}

extern "C" void kernel_launch(void* const* d_in, const int* in_sizes, int n_in,
                              void* d_out, int out_size, void* d_ws, size_t ws_size,
                              hipStream_t stream) {
    const float* x = (const float*)d_in[0];   // [64, 4096]
    const float* W = (const float*)d_in[1];   // [1, 32]
    const int*   I = (const int*)d_in[2];     // [32, 4096, 16, 4]
    float* out = (float*)d_out;               // [64, 4096]

    float* ws   = (float*)d_ws;
    float* Rt   = ws;                  // 262144 floats  [G,B]
    float* H    = ws + 262144;         // 262144
    float* Lraw = ws + 524288;         // 262144
    float* maxb = ws + 786432;         // 4 steps * 64 floats of atomic buffers
    float* Cs   = ws + 1048576;        // 32 * 262144 = 8388608 floats (32 MB)

    hipMemsetAsync(maxb, 0, NSTEP * 64 * sizeof(float), stream);
    k_transpose<<<Gv / 64, 256, 0, stream>>>(x, Rt);

    for (int step = 0; step < NSTEP; ++step) {
        float* Mc = maxb + step * 64;  // [32] per-clause maxima
        float* Hm = Mc + 32;
        float* Lm = Mc + 33;
        k_clauses<<<(Cv * Gv) / 16, 256, 0, stream>>>((const float4*)Rt, (const int4*)I,
                                                      (float4*)Cs, Mc);
        k_combine<<<(Bv * Gv) / 256, 256, 0, stream>>>(Cs, W, Mc, H, Hm);
        k_update <<<(Bv * Gv) / 256, 256, 0, stream>>>(Rt, H, Hm, Lraw, Lm);
        k_norm   <<<(Bv * Gv) / 256, 256, 0, stream>>>(Lraw, Lm, Rt, out, step == NSTEP - 1);
    }
}

// Round 3
// 570.924 us; speedup vs baseline: 2.5758x; 1.5553x over previous
//
#include <hip/hip_runtime.h>

#define Bv 64
#define Gv 4096
#define Cv 32
#define Sv 16
#define Lv 4
#define NSTEP 4
#define LOG2E 1.4426950408889634f
#define LN2   0.6931471805599453f
#define GAMMA 0.01f
#define RLOG2E_G 144.26950408889634f   // LOG2E / GAMMA

__device__ __forceinline__ float wave_max(float v) {
#pragma unroll
    for (int off = 32; off > 0; off >>= 1)
        v = fmaxf(v, __shfl_xor(v, off, 64));
    return v;
}

// 256-thread block -> one atomicMax (values all >= 0, so int-bit compare == float compare)
__device__ __forceinline__ void block_atomic_max(float v, float* dst, float* smax) {
    v = wave_max(v);
    int lane = threadIdx.x & 63;
    int wid  = threadIdx.x >> 6;
    if (lane == 0) smax[wid] = v;
    __syncthreads();
    if (threadIdx.x == 0) {
        float m = fmaxf(fmaxf(smax[0], smax[1]), fmaxf(smax[2], smax[3]));
        atomicMax((int*)dst, __float_as_int(m));
    }
}

// x [B,G] -> Rt [G,B]   (LDS-tiled transpose, 64 g per block)
__global__ __launch_bounds__(256) void k_transpose(const float* __restrict__ x,
                                                   float* __restrict__ Rt) {
    __shared__ float tile[64][65];
    int g0 = blockIdx.x * 64;
#pragma unroll
    for (int i = 0; i < 16; ++i) {
        int t = threadIdx.x + i * 256;
        int b = t >> 6, gi = t & 63;
        tile[gi][b] = x[b * Gv + g0 + gi];
    }
    __syncthreads();
#pragma unroll
    for (int i = 0; i < 16; ++i) {
        int t = threadIdx.x + i * 256;
        int gi = t >> 6, b = t & 63;
        Rt[(g0 + gi) * 64 + b] = tile[gi][b];
    }
}

// Lane = (g_sub 0..3, bg 0..15). Each lane owns batches 4bg..4bg+3 (float4) of
// grounding g = g0 + g_sub. One wave covers 4 g; block (4 waves) covers 16 g of one c.
// Online (flash-style) LSE over s: no p[] staging -> no spills.
__global__ __launch_bounds__(256, 4) void k_clauses(const float4* __restrict__ Rt4,
                                                    const int4* __restrict__ I4,
                                                    float4* __restrict__ Cs4,
                                                    float* __restrict__ Mc) {
    __shared__ float smax[4];
    int lane = threadIdx.x & 63;
    int wid  = threadIdx.x >> 6;
    int bg   = lane & 15;
    int gsub = lane >> 4;
    int blk  = blockIdx.x;              // 8192 blocks
    int c    = blk >> 8;                // 256 blocks per clause
    int g    = ((blk & 255) << 4) + (wid << 2) + gsub;
    const int4* __restrict__ Ig = I4 + (size_t)(c * Gv + g) * Sv;

    float4 m   = make_float4(0.f, 0.f, 0.f, 0.f);   // products are >= 0
    float4 sum = make_float4(0.f, 0.f, 0.f, 0.f);
#pragma unroll
    for (int s = 0; s < Sv; ++s) {
        int4 ii = Ig[s];
        float4 a = Rt4[((size_t)(unsigned)ii.x << 4) + bg];
        float4 b = Rt4[((size_t)(unsigned)ii.y << 4) + bg];
        float4 e = Rt4[((size_t)(unsigned)ii.z << 4) + bg];
        float4 d = Rt4[((size_t)(unsigned)ii.w << 4) + bg];
        float4 p = make_float4(a.x * b.x * e.x * d.x,
                               a.y * b.y * e.y * d.y,
                               a.z * b.z * e.z * d.z,
                               a.w * b.w * e.w * d.w);
        float4 nm;
        nm.x = fmaxf(m.x, p.x); nm.y = fmaxf(m.y, p.y);
        nm.z = fmaxf(m.z, p.z); nm.w = fmaxf(m.w, p.w);
        sum.x = sum.x * exp2f((m.x - nm.x) * RLOG2E_G) + exp2f((p.x - nm.x) * RLOG2E_G);
        sum.y = sum.y * exp2f((m.y - nm.y) * RLOG2E_G) + exp2f((p.y - nm.y) * RLOG2E_G);
        sum.z = sum.z * exp2f((m.z - nm.z) * RLOG2E_G) + exp2f((p.z - nm.z) * RLOG2E_G);
        sum.w = sum.w * exp2f((m.w - nm.w) * RLOG2E_G) + exp2f((p.w - nm.w) * RLOG2E_G);
        m = nm;
    }

    float4 ls;
    ls.x = m.x + GAMMA * (LN2 * log2f(sum.x));
    ls.y = m.y + GAMMA * (LN2 * log2f(sum.y));
    ls.z = m.z + GAMMA * (LN2 * log2f(sum.z));
    ls.w = m.w + GAMMA * (LN2 * log2f(sum.w));

    Cs4[((size_t)(c * Gv + g) << 4) + bg] = ls;

    float v = fmaxf(fmaxf(ls.x, ls.y), fmaxf(ls.z, ls.w));
    block_atomic_max(v, Mc + c, smax);      // c uniform across block
}

// H[b,g] = sum_c softmax(W)[c] * Cs[c,b,g] / max(Mc[c],1) ; track global max
__global__ __launch_bounds__(256) void k_combine(const float* __restrict__ Cs,
                                                 const float* __restrict__ W,
                                                 const float* __restrict__ Mc,
                                                 float* __restrict__ H,
                                                 float* __restrict__ Hmax) {
    __shared__ float smax[4];
    int tid = blockIdx.x * 256 + threadIdx.x;
    float e[Cv];
    float wsum = 0.0f;
#pragma unroll
    for (int c = 0; c < Cv; ++c) { e[c] = exp2f(W[c] * LOG2E); wsum += e[c]; }
    float rw = 1.0f / wsum;
    float h = 0.0f;
#pragma unroll
    for (int c = 0; c < Cv; ++c) {
        float coef = e[c] * rw / fmaxf(Mc[c], 1.0f);
        h += coef * Cs[(size_t)c * (Gv * 64) + tid];
    }
    H[tid] = h;
    block_atomic_max(h, Hmax, smax);
}

// ls = softor2(R, H/max(Hmax,1)) un-normalized ; track global max
__global__ __launch_bounds__(256) void k_update(const float* __restrict__ Rt,
                                                const float* __restrict__ H,
                                                const float* __restrict__ Hmax,
                                                float* __restrict__ Lraw,
                                                float* __restrict__ Lmax) {
    __shared__ float smax[4];
    int tid = blockIdx.x * 256 + threadIdx.x;
    float hden = fmaxf(Hmax[0], 1.0f);
    float hn = H[tid] / hden;
    float r  = Rt[tid];
    float mx = fmaxf(r, hn), mn = fminf(r, hn);
    float t  = exp2f((mn - mx) * RLOG2E_G);
    float ls = mx + GAMMA * (LN2 * log2f(1.0f + t));
    Lraw[tid] = ls;
    block_atomic_max(ls, Lmax, smax);
}

// R = Lraw / max(Lmax,1); last step writes output in [B,G] layout
__global__ __launch_bounds__(256) void k_norm(const float* __restrict__ Lraw,
                                              const float* __restrict__ Lmax,
                                              float* __restrict__ Rt,
                                              float* __restrict__ out,
                                              int last) {
    int tid = blockIdx.x * 256 + threadIdx.x;
    float d = fmaxf(Lmax[0], 1.0f);
    float v = Lraw[tid] / d;
    if (last) {
        int g = tid >> 6, b = tid & 63;
        out[b * Gv + g] = v;
    } else {
        Rt[tid] = v;
    }
}

extern "C" void kernel_launch(void* const* d_in, const int* in_sizes, int n_in,
                              void* d_out, int out_size, void* d_ws, size_t ws_size,
                              hipStream_t stream) {
    const float* x = (const float*)d_in[0];   // [64, 4096]
    const float* W = (const float*)d_in[1];   // [1, 32]
    const int*   I = (const int*)d_in[2];     // [32, 4096, 16, 4]
    float* out = (float*)d_out;               // [64, 4096]

    float* ws   = (float*)d_ws;
    float* Rt   = ws;                  // 262144 floats  [G,B]
    float* H    = ws + 262144;         // 262144
    float* Lraw = ws + 524288;         // 262144
    float* maxb = ws + 786432;         // 4 steps * 64 floats of atomic buffers
    float* Cs   = ws + 1048576;        // 32 * 262144 = 8388608 floats (32 MB)

    hipMemsetAsync(maxb, 0, NSTEP * 64 * sizeof(float), stream);
    k_transpose<<<Gv / 64, 256, 0, stream>>>(x, Rt);

    for (int step = 0; step < NSTEP; ++step) {
        float* Mc = maxb + step * 64;  // [32] per-clause maxima
        float* Hm = Mc + 32;
        float* Lm = Mc + 33;
        k_clauses<<<(Cv * Gv) / 16, 256, 0, stream>>>((const float4*)Rt, (const int4*)I,
                                                      (float4*)Cs, Mc);
        k_combine<<<(Bv * Gv) / 256, 256, 0, stream>>>(Cs, W, Mc, H, Hm);
        k_update <<<(Bv * Gv) / 256, 256, 0, stream>>>(Rt, H, Hm, Lraw, Lm);
        k_norm   <<<(Bv * Gv) / 256, 256, 0, stream>>>(Lraw, Lm, Rt, out, step == NSTEP - 1);
    }
}

// Round 4
// 527.208 us; speedup vs baseline: 2.7894x; 1.0829x over previous
//
#include <hip/hip_runtime.h>

#define Bv 64
#define Gv 4096
#define Cv 32
#define Sv 16
#define Lv 4
#define NSTEP 4
#define LOG2E 1.4426950408889634f
#define LN2   0.6931471805599453f
#define GAMMA 0.01f
#define RLOG2E_G 144.26950408889634f   // LOG2E / GAMMA

// raw HW transcendentals: v_exp_f32 / v_log_f32 (base-2). Safe here:
// exp2 args in [-144.3, 0] (flushed denormal result => term provably negligible),
// log2 args in [1, 16+] (sum always >= 1 because the running-max term contributes 1).
#define EXP2R(x) __builtin_amdgcn_exp2f(x)
#define LOG2R(x) __builtin_amdgcn_logf(x)

__device__ __forceinline__ float wave_max(float v) {
#pragma unroll
    for (int off = 32; off > 0; off >>= 1)
        v = fmaxf(v, __shfl_xor(v, off, 64));
    return v;
}

// 256-thread block -> one atomicMax (values all >= 0, so int-bit compare == float compare)
__device__ __forceinline__ void block_atomic_max(float v, float* dst, float* smax) {
    v = wave_max(v);
    int lane = threadIdx.x & 63;
    int wid  = threadIdx.x >> 6;
    if (lane == 0) smax[wid] = v;
    __syncthreads();
    if (threadIdx.x == 0) {
        float m = fmaxf(fmaxf(smax[0], smax[1]), fmaxf(smax[2], smax[3]));
        atomicMax((int*)dst, __float_as_int(m));
    }
}

// x [B,G] -> Rt [G,B]   (LDS-tiled transpose, 64 g per block)
__global__ __launch_bounds__(256) void k_transpose(const float* __restrict__ x,
                                                   float* __restrict__ Rt) {
    __shared__ float tile[64][65];
    int g0 = blockIdx.x * 64;
#pragma unroll
    for (int i = 0; i < 16; ++i) {
        int t = threadIdx.x + i * 256;
        int b = t >> 6, gi = t & 63;
        tile[gi][b] = x[b * Gv + g0 + gi];
    }
    __syncthreads();
#pragma unroll
    for (int i = 0; i < 16; ++i) {
        int t = threadIdx.x + i * 256;
        int gi = t >> 6, b = t & 63;
        Rt[(g0 + gi) * 64 + b] = tile[gi][b];
    }
}

// Lane = (g_sub 0..3, bg 0..15). Each lane owns batches 4bg..4bg+3 (float4) of
// grounding g = g0 + g_sub. One wave covers 4 g; block (4 waves) covers 16 g of one c.
// Online (flash-style) LSE over s: no p[] staging -> no spills.
__global__ __launch_bounds__(256, 4) void k_clauses(const float4* __restrict__ Rt4,
                                                    const int4* __restrict__ I4,
                                                    float4* __restrict__ Cs4,
                                                    float* __restrict__ Mc) {
    __shared__ float smax[4];
    int lane = threadIdx.x & 63;
    int wid  = threadIdx.x >> 6;
    int bg   = lane & 15;
    int gsub = lane >> 4;
    int blk  = blockIdx.x;              // 8192 blocks
    int c    = blk >> 8;                // 256 blocks per clause
    int g    = ((blk & 255) << 4) + (wid << 2) + gsub;
    const int4* __restrict__ Ig = I4 + (size_t)(c * Gv + g) * Sv;

    float4 m   = make_float4(0.f, 0.f, 0.f, 0.f);   // products are >= 0
    float4 sum = make_float4(0.f, 0.f, 0.f, 0.f);
#pragma unroll
    for (int s = 0; s < Sv; ++s) {
        int4 ii = Ig[s];
        float4 a = Rt4[((size_t)(unsigned)ii.x << 4) + bg];
        float4 b = Rt4[((size_t)(unsigned)ii.y << 4) + bg];
        float4 e = Rt4[((size_t)(unsigned)ii.z << 4) + bg];
        float4 d = Rt4[((size_t)(unsigned)ii.w << 4) + bg];
        float4 p = make_float4(a.x * b.x * e.x * d.x,
                               a.y * b.y * e.y * d.y,
                               a.z * b.z * e.z * d.z,
                               a.w * b.w * e.w * d.w);
        float4 nm;
        nm.x = fmaxf(m.x, p.x); nm.y = fmaxf(m.y, p.y);
        nm.z = fmaxf(m.z, p.z); nm.w = fmaxf(m.w, p.w);
        sum.x = sum.x * EXP2R((m.x - nm.x) * RLOG2E_G) + EXP2R((p.x - nm.x) * RLOG2E_G);
        sum.y = sum.y * EXP2R((m.y - nm.y) * RLOG2E_G) + EXP2R((p.y - nm.y) * RLOG2E_G);
        sum.z = sum.z * EXP2R((m.z - nm.z) * RLOG2E_G) + EXP2R((p.z - nm.z) * RLOG2E_G);
        sum.w = sum.w * EXP2R((m.w - nm.w) * RLOG2E_G) + EXP2R((p.w - nm.w) * RLOG2E_G);
        m = nm;
    }

    float4 ls;
    ls.x = fmaf(GAMMA * LN2, LOG2R(sum.x), m.x);
    ls.y = fmaf(GAMMA * LN2, LOG2R(sum.y), m.y);
    ls.z = fmaf(GAMMA * LN2, LOG2R(sum.z), m.z);
    ls.w = fmaf(GAMMA * LN2, LOG2R(sum.w), m.w);

    Cs4[((size_t)(c * Gv + g) << 4) + bg] = ls;

    float v = fmaxf(fmaxf(ls.x, ls.y), fmaxf(ls.z, ls.w));
    block_atomic_max(v, Mc + c, smax);      // c uniform across block
}

// coef[c] = softmax(W)[c] / max(Mc[c], 1)   -- one wave, lanes 0..31
__global__ __launch_bounds__(64) void k_coef(const float* __restrict__ W,
                                             const float* __restrict__ Mc,
                                             float* __restrict__ coef) {
    int c = threadIdx.x;                  // launched with 32 threads
    float e = EXP2R(W[c] * LOG2E);
    float wsum = e;
#pragma unroll
    for (int off = 16; off > 0; off >>= 1)
        wsum += __shfl_xor(wsum, off, 64);
    coef[c] = e / (wsum * fmaxf(Mc[c], 1.0f));
}

// H[b,g] = sum_c coef[c] * Cs[c,b,g] ; track global max.  float4 per thread.
__global__ __launch_bounds__(256) void k_combine(const float4* __restrict__ Cs4,
                                                 const float* __restrict__ coef,
                                                 float4* __restrict__ H4,
                                                 float* __restrict__ Hmax) {
    __shared__ float smax[4];
    int tid = blockIdx.x * 256 + threadIdx.x;     // 0 .. B*G/4-1
    float4 h = make_float4(0.f, 0.f, 0.f, 0.f);
#pragma unroll
    for (int c = 0; c < Cv; ++c) {
        float w = coef[c];                         // uniform -> scalar load
        float4 v = Cs4[(size_t)c * (Gv * 16) + tid];
        h.x = fmaf(w, v.x, h.x); h.y = fmaf(w, v.y, h.y);
        h.z = fmaf(w, v.z, h.z); h.w = fmaf(w, v.w, h.w);
    }
    H4[tid] = h;
    float v = fmaxf(fmaxf(h.x, h.y), fmaxf(h.z, h.w));
    block_atomic_max(v, Hmax, smax);
}

// ls = softor2(R, H/max(Hmax,1)) un-normalized ; track global max
__global__ __launch_bounds__(256) void k_update(const float* __restrict__ Rt,
                                                const float* __restrict__ H,
                                                const float* __restrict__ Hmax,
                                                float* __restrict__ Lraw,
                                                float* __restrict__ Lmax) {
    __shared__ float smax[4];
    int tid = blockIdx.x * 256 + threadIdx.x;
    float hden = fmaxf(Hmax[0], 1.0f);
    float hn = H[tid] / hden;
    float r  = Rt[tid];
    float mx = fmaxf(r, hn), mn = fminf(r, hn);
    float t  = EXP2R((mn - mx) * RLOG2E_G);
    float ls = fmaf(GAMMA * LN2, LOG2R(1.0f + t), mx);
    Lraw[tid] = ls;
    block_atomic_max(ls, Lmax, smax);
}

// R = Lraw / max(Lmax,1); last step writes output in [B,G] layout
__global__ __launch_bounds__(256) void k_norm(const float* __restrict__ Lraw,
                                              const float* __restrict__ Lmax,
                                              float* __restrict__ Rt,
                                              float* __restrict__ out,
                                              int last) {
    int tid = blockIdx.x * 256 + threadIdx.x;
    float d = fmaxf(Lmax[0], 1.0f);
    float v = Lraw[tid] / d;
    if (last) {
        int g = tid >> 6, b = tid & 63;
        out[b * Gv + g] = v;
    } else {
        Rt[tid] = v;
    }
}

extern "C" void kernel_launch(void* const* d_in, const int* in_sizes, int n_in,
                              void* d_out, int out_size, void* d_ws, size_t ws_size,
                              hipStream_t stream) {
    const float* x = (const float*)d_in[0];   // [64, 4096]
    const float* W = (const float*)d_in[1];   // [1, 32]
    const int*   I = (const int*)d_in[2];     // [32, 4096, 16, 4]
    float* out = (float*)d_out;               // [64, 4096]

    float* ws   = (float*)d_ws;
    float* Rt   = ws;                  // 262144 floats  [G,B]
    float* H    = ws + 262144;         // 262144
    float* Lraw = ws + 524288;         // 262144
    float* maxb = ws + 786432;         // 4 steps * 128 floats (atomics + coef)
    float* Cs   = ws + 1048576;        // 32 * 262144 = 8388608 floats (32 MB)

    hipMemsetAsync(maxb, 0, NSTEP * 128 * sizeof(float), stream);
    k_transpose<<<Gv / 64, 256, 0, stream>>>(x, Rt);

    for (int step = 0; step < NSTEP; ++step) {
        float* Mc   = maxb + step * 128;  // [32] per-clause maxima
        float* Hm   = Mc + 32;
        float* Lm   = Mc + 33;
        float* coef = Mc + 64;            // [32]
        k_clauses<<<(Cv * Gv) / 16, 256, 0, stream>>>((const float4*)Rt, (const int4*)I,
                                                      (float4*)Cs, Mc);
        k_coef   <<<1, 32, 0, stream>>>(W, Mc, coef);
        k_combine<<<(Bv * Gv) / 1024, 256, 0, stream>>>((const float4*)Cs, coef,
                                                        (float4*)H, Hm);
        k_update <<<(Bv * Gv) / 256, 256, 0, stream>>>(Rt, H, Hm, Lraw, Lm);
        k_norm   <<<(Bv * Gv) / 256, 256, 0, stream>>>(Lraw, Lm, Rt, out, step == NSTEP - 1);
    }
}